// Round 10
// baseline (533.646 us; speedup 1.0000x reference)
//
#include <hip/hip_runtime.h>
#include <hip/hip_bf16.h>
#include <math.h>

// Problem constants (fixed by the reference)
#define NPTS 50000   // N data points
#define DIM  256     // feature dim (K of the GEMM)
#define BQ   2048    // batch of queries (M of the GEMM)
#define NPAD 50048   // N padded to multiple of 128

#define CH   128     // n-rows per LDS chunk (fp8: 32 KB)
#define NCH  391     // NPAD/CH
#define NG   48      // n-groups; grid = 16 m-tiles x 48 groups = 768
#define LOG2E 1.4426950408889634f

#if __has_builtin(__builtin_amdgcn_mfma_f32_16x16x32_fp8_fp8) && \
    __has_builtin(__builtin_amdgcn_cvt_pk_fp8_f32)
#define HAVE_FP8 1
#else
#define HAVE_FP8 0
#endif

// ---------- fp8 fast-path ws layout (float offsets) ----------
//  acc   [0,      2048)
//  x2h   [2048,   4096)    0.5*log2e*||x||^2
//  t     [4096,  54144)    0.5*log2e*||s||^2 - log2|w|  (+inf when w==0)
//  sgn   [54144, 104192)   label sign
//  xb8   [104192, 235264)  fp8 x rows (256 B each)
//  sb8   [235264, 3438336) fp8 s rows (NPAD, zero-padded)
#define WS_ACC 0
#define WS_X2  2048
#define WS_T   4096
#define WS_SGN 54144
#define WS_XB8 104192
#define WS_SB8 235264
#define WS_FP8_BYTES (3438336ull * 4ull)   // 13,753,344 B

// ---------- v1 fallback layout ----------
#define V1_ACC 0
#define V1_X2  2048
#define V1_S2  4096
#define V1_W   54096

typedef __bf16 bf16x8 __attribute__((ext_vector_type(8)));
typedef __bf16 bf16x4 __attribute__((ext_vector_type(4)));
typedef float  f32x4  __attribute__((ext_vector_type(4)));
typedef long   i64x2  __attribute__((ext_vector_type(2)));
typedef unsigned int u32;

__device__ __forceinline__ float fast_exp2(float v) {
#if __has_builtin(__builtin_amdgcn_exp2f)
  return __builtin_amdgcn_exp2f(v);   // raw v_exp_f32
#else
  return exp2f(v);
#endif
}

__device__ __forceinline__ void async_copy16(const void* g, void* l) {
  __builtin_amdgcn_global_load_lds(
      (const __attribute__((address_space(1))) u32*)g,
      (__attribute__((address_space(3))) u32*)l, 16, 0, 0);
}

#if HAVE_FP8
// ============================================================
// FP8 FAST PATH (non-scaled v_mfma_f32_16x16x32_fp8_fp8)
// ============================================================

// One wave per row: fp32 -> fp8 e4m3 convert into ws, plus folded epilogue
// constants t = s2h - log2|w| and sign. Blocks 0..7 zero the accumulator.
__global__ __launch_bounds__(256) void svm_precvt10(
    const float* __restrict__ x, const float* __restrict__ s,
    const float* __restrict__ labels, const float* __restrict__ lambdas,
    float* __restrict__ ws) {
  const int wid  = blockIdx.x * 4 + (threadIdx.x >> 6);
  const int lane = threadIdx.x & 63;
  int* xb8 = (int*)(ws + WS_XB8);
  int* sb8 = (int*)(ws + WS_SB8);

  if (blockIdx.x < 8) ws[WS_ACC + blockIdx.x * 256 + threadIdx.x] = 0.0f;

  if (wid < NPAD) {
    float4 v = make_float4(0.f, 0.f, 0.f, 0.f);
    if (wid < NPTS)
      v = reinterpret_cast<const float4*>(s + (size_t)wid * DIM)[lane];
    int pk = __builtin_amdgcn_cvt_pk_fp8_f32(v.x, v.y, 0, false);
    pk     = __builtin_amdgcn_cvt_pk_fp8_f32(v.z, v.w, pk, true);
    sb8[(size_t)wid * 64 + lane] = pk;
    float ss = v.x * v.x + v.y * v.y + v.z * v.z + v.w * v.w;
    #pragma unroll
    for (int off = 32; off > 0; off >>= 1) ss += __shfl_xor(ss, off);
    if (lane == 0) {
      float s2h = 0.5f * LOG2E * ss;
      float lam = (wid < NPTS) ? lambdas[wid] : 0.0f;
      float lab = (wid < NPTS) ? labels[wid] : 1.0f;
      float mag = lam > 0.0f ? lam : 0.0f;
      ws[WS_T + wid]   = (mag > 0.0f) ? s2h - log2f(mag) : __builtin_inff();
      ws[WS_SGN + wid] = lab;
    }
  } else if (wid < NPAD + BQ) {
    int r = wid - NPAD;
    float4 v = reinterpret_cast<const float4*>(x + (size_t)r * DIM)[lane];
    int pk = __builtin_amdgcn_cvt_pk_fp8_f32(v.x, v.y, 0, false);
    pk     = __builtin_amdgcn_cvt_pk_fp8_f32(v.z, v.w, pk, true);
    xb8[(size_t)r * 64 + lane] = pk;
    float ss = v.x * v.x + v.y * v.y + v.z * v.z + v.w * v.w;
    #pragma unroll
    for (int off = 32; off > 0; off >>= 1) ss += __shfl_xor(ss, off);
    if (lane == 0) ws[WS_X2 + r] = 0.5f * LOG2E * ss;
  }
}

// main9 skeleton in fp8: halves LDS read bytes (the 31-us dominant pipe),
// halves staging, A pinned in 32 VGPR. Row = 256 B fp8 = 16 slots of 16 B;
// LDS stores [n][256B] with slot swizzle phys_p holds logical p^(n&15)
// -> both staging writes and fragment reads are conflict-free.
// k-window (quad q, pair kp, half h) = row bytes [(q*4+kp)*16 + h*8, +8),
// applied identically to A and B (dot invariant under shared k-permutation).
__global__ __launch_bounds__(256, 2) void svm_main10(float* __restrict__ ws) {
  __shared__ char sB[CH * 256];  // 32 KB

  const char* xb8 = (const char*)(ws + WS_XB8);
  const char* sb8 = (const char*)(ws + WS_SB8);
  const float* x2g = ws + WS_X2;
  const float* tg  = ws + WS_T;
  const float* sgg = ws + WS_SGN;
  float* accOut    = ws + WS_ACC;

  const int t    = threadIdx.x;
  const int wave = t >> 6;
  const int lane = t & 63;
  const int quad = lane >> 4;
  const int l16  = lane & 15;
  const int g    = blockIdx.x % NG;
  const int mt   = blockIdx.x / NG;       // 0..15
  const int m0w  = mt * 128 + wave * 32;  // this wave's 32 m-rows
  const int c0   = (NCH * g) / NG;
  const int c1   = (NCH * (g + 1)) / NG;

  // A pinned: 2 mi x 4 kp x 16 B = 32 VGPR.
  f32x4 afr[2][4];
  #pragma unroll
  for (int mi = 0; mi < 2; ++mi)
    #pragma unroll
    for (int kp = 0; kp < 4; ++kp)
      afr[mi][kp] = *reinterpret_cast<const f32x4*>(
          xb8 + (size_t)(m0w + mi * 16 + l16) * 256 + quad * 64 + kp * 16);
  #pragma unroll
  for (int mi = 0; mi < 2; ++mi)
    #pragma unroll
    for (int kp = 0; kp < 4; ++kp)
      asm volatile("" : "+v"(afr[mi][kp]));  // no remat, stays in VGPRs

  float runAcc[2][4] = {{0.f, 0.f, 0.f, 0.f}, {0.f, 0.f, 0.f, 0.f}};

  // staging per-lane coords: instr j stages rows j*4..j*4+3 (1 KB).
  const int rowin = lane >> 4;   // 0..3 row within the 4-row group
  const int p     = lane & 15;   // phys slot

  for (int c = c0; c < c1; ++c) {
    __syncthreads();  // prior chunk's LDS reads done

    #pragma unroll
    for (int i = 0; i < 8; ++i) {
      int j = wave * 8 + i;                          // 0..31
      int n15 = ((j & 3) * 4 + rowin) & 15;          // (j*4+rowin) & 15
      const char* src = sb8 + (size_t)(c * CH + j * 4) * 256
                            + rowin * 256 + ((p ^ n15) * 16);
      async_copy16(src, sB + j * 1024 + lane * 16);
    }
    __syncthreads();  // vmcnt drain

    f32x4 acc[2][8];
    #pragma unroll
    for (int mi = 0; mi < 2; ++mi)
      #pragma unroll
      for (int ni = 0; ni < 8; ++ni)
        acc[mi][ni] = (f32x4)(0.0f);

    #pragma unroll
    for (int kp = 0; kp < 4; ++kp) {
      f32x4 bfp[8];
      #pragma unroll
      for (int ni = 0; ni < 8; ++ni) {
        int n = ni * 16 + l16;   // n & 15 == l16
        bfp[ni] = *reinterpret_cast<const f32x4*>(
            sB + n * 256 + (((quad * 4 + kp) ^ l16) * 16));
      }
      #pragma unroll
      for (int h = 0; h < 2; ++h) {
        #pragma unroll
        for (int mi = 0; mi < 2; ++mi) {
          long av = __builtin_bit_cast(i64x2, afr[mi][kp])[h];
          #pragma unroll
          for (int ni = 0; ni < 8; ++ni) {
            long bv = __builtin_bit_cast(i64x2, bfp[ni])[h];
            acc[mi][ni] = __builtin_amdgcn_mfma_f32_16x16x32_fp8_fp8(
                av, bv, acc[mi][ni], 0, 0, 0);
          }
        }
      }
    }

    // Hoisted epilogue: p += sgn * exp2(c*log2e - t_n); x2 applied at end.
    float tt[8], sg[8];
    #pragma unroll
    for (int ni = 0; ni < 8; ++ni) {
      int n = c * CH + ni * 16 + l16;
      tt[ni] = tg[n];
      sg[ni] = sgg[n];
    }
    #pragma unroll
    for (int mi = 0; mi < 2; ++mi)
      #pragma unroll
      for (int reg = 0; reg < 4; ++reg) {
        float pacc = runAcc[mi][reg];
        #pragma unroll
        for (int ni = 0; ni < 8; ++ni)
          pacc = __builtin_fmaf(sg[ni],
                   fast_exp2(__builtin_fmaf(acc[mi][ni][reg], LOG2E, -tt[ni])),
                   pacc);
        runAcc[mi][reg] = pacc;
      }
  }

  // reduce over the 16 n-column lanes; scale by exp2(-x2h); one atomic/row.
  #pragma unroll
  for (int mi = 0; mi < 2; ++mi)
    #pragma unroll
    for (int reg = 0; reg < 4; ++reg) {
      float v = runAcc[mi][reg];
      v += __shfl_xor(v, 1);
      v += __shfl_xor(v, 2);
      v += __shfl_xor(v, 4);
      v += __shfl_xor(v, 8);
      if (l16 == 0) {
        int row = m0w + mi * 16 + quad * 4 + reg;
        atomicAdd(&accOut[row], fast_exp2(-x2g[row]) * v);
      }
    }
}
#endif  // HAVE_FP8

// ============================================================
// V1 FALLBACK (used only if ws too small or fp8 builtins absent)
// ============================================================

__global__ __launch_bounds__(256) void svm_precompute(
    const float* __restrict__ x, const float* __restrict__ s,
    const float* __restrict__ labels, const float* __restrict__ lambdas,
    float* __restrict__ ws) {
  int wid  = blockIdx.x * 4 + (threadIdx.x >> 6);
  int lane = threadIdx.x & 63;
  const float* src;
  if (wid < NPTS)           src = s + (size_t)wid * DIM;
  else if (wid < NPTS + BQ) src = x + (size_t)(wid - NPTS) * DIM;
  else return;
  float4 v = reinterpret_cast<const float4*>(src)[lane];
  float ss = v.x * v.x + v.y * v.y + v.z * v.z + v.w * v.w;
  #pragma unroll
  for (int off = 32; off > 0; off >>= 1) ss += __shfl_xor(ss, off);
  if (lane == 0) {
    if (wid < NPTS) {
      ws[V1_S2 + wid] = ss;
      float lam = lambdas[wid];
      ws[V1_W + wid] = labels[wid] * (lam > 0.0f ? lam : 0.0f);
    } else {
      ws[V1_X2 + (wid - NPTS)] = ss;
    }
  }
}

__global__ __launch_bounds__(256) void svm_main(
    const float* __restrict__ x, const float* __restrict__ s,
    const float* __restrict__ ws) {
  __shared__ __bf16 sA[128 * 32];
  __shared__ __bf16 sB2[128 * 32];

  const int t    = threadIdx.x;
  const int wave = t >> 6;
  const int lane = t & 63;
  const int quad = lane >> 4;
  const int l16  = lane & 15;
  const int wm   = (wave & 1) * 64;
  const int wn   = (wave >> 1) * 64;
  const int bRow0 = blockIdx.y * 128;
  const int n0    = blockIdx.x * 128;

  f32x4 acc[4][4];
  #pragma unroll
  for (int i = 0; i < 4; ++i)
    #pragma unroll
    for (int j = 0; j < 4; ++j)
      acc[i][j] = (f32x4)(0.0f);

  for (int kt = 0; kt < DIM / 32; ++kt) {
    const int k0 = kt * 32;
    __syncthreads();
    #pragma unroll
    for (int i = 0; i < 4; ++i) {
      int slot = t + i * 256;
      int r  = slot >> 3;
      int c4 = slot & 7;
      float4 va = reinterpret_cast<const float4*>(
          x + (size_t)(bRow0 + r) * DIM + k0)[c4];
      bf16x4 ha = { (__bf16)va.x, (__bf16)va.y, (__bf16)va.z, (__bf16)va.w };
      *reinterpret_cast<bf16x4*>(&sA[r * 32 + c4 * 4]) = ha;

      int nrow = n0 + r;
      float4 vb = make_float4(0.f, 0.f, 0.f, 0.f);
      if (nrow < NPTS)
        vb = reinterpret_cast<const float4*>(
            s + (size_t)nrow * DIM + k0)[c4];
      bf16x4 hb = { (__bf16)vb.x, (__bf16)vb.y, (__bf16)vb.z, (__bf16)vb.w };
      *reinterpret_cast<bf16x4*>(&sB2[r * 32 + c4 * 4]) = hb;
    }
    __syncthreads();

    bf16x8 af[4], bfv[4];
    #pragma unroll
    for (int mi = 0; mi < 4; ++mi)
      af[mi] = *reinterpret_cast<const bf16x8*>(
          &sA[(wm + mi * 16 + l16) * 32 + quad * 8]);
    #pragma unroll
    for (int ni = 0; ni < 4; ++ni)
      bfv[ni] = *reinterpret_cast<const bf16x8*>(
          &sB2[(wn + ni * 16 + l16) * 32 + quad * 8]);
    #pragma unroll
    for (int mi = 0; mi < 4; ++mi)
      #pragma unroll
      for (int ni = 0; ni < 4; ++ni)
        acc[mi][ni] = __builtin_amdgcn_mfma_f32_16x16x32_bf16(
            af[mi], bfv[ni], acc[mi][ni], 0, 0, 0);
  }

  const float* x2g = ws + V1_X2;
  const float* s2g = ws + V1_S2;
  const float* wg  = ws + V1_W;
  float* accOut    = (float*)ws + V1_ACC;

  float s2v[4], wv[4];
  #pragma unroll
  for (int ni = 0; ni < 4; ++ni) {
    int n = n0 + wn + ni * 16 + l16;
    bool ok = n < NPTS;
    s2v[ni] = ok ? s2g[n] : 0.0f;
    wv[ni]  = ok ? wg[n]  : 0.0f;
  }
  #pragma unroll
  for (int mi = 0; mi < 4; ++mi) {
    const int mbase = wm + mi * 16 + quad * 4;
    #pragma unroll
    for (int reg = 0; reg < 4; ++reg) {
      float x2r = x2g[bRow0 + mbase + reg];
      float ps = 0.0f;
      #pragma unroll
      for (int ni = 0; ni < 4; ++ni) {
        float cc = acc[mi][ni][reg];
        ps += __expf(__builtin_fmaf(-0.5f, x2r + s2v[ni], cc)) * wv[ni];
      }
      ps += __shfl_xor(ps, 1);
      ps += __shfl_xor(ps, 2);
      ps += __shfl_xor(ps, 4);
      ps += __shfl_xor(ps, 8);
      if (l16 == 0) atomicAdd(&accOut[bRow0 + mbase + reg], ps);
    }
  }
}

// ============================================================

__global__ __launch_bounds__(256) void svm_finalize(
    const float* __restrict__ ws, const float* __restrict__ bias,
    float* __restrict__ out) {
  int i = blockIdx.x * 256 + threadIdx.x;
  if (i < BQ) out[i] = tanhf(ws[i] + bias[0]);  // acc at offset 0 in all layouts
}

extern "C" void kernel_launch(void* const* d_in, const int* in_sizes, int n_in,
                              void* d_out, int out_size, void* d_ws, size_t ws_size,
                              hipStream_t stream) {
  const float* x       = (const float*)d_in[0];  // [2048, 256]
  const float* s       = (const float*)d_in[1];  // [50000, 256]
  const float* labels  = (const float*)d_in[2];  // [50000]
  const float* lambdas = (const float*)d_in[3];  // [50000]
  const float* bias    = (const float*)d_in[4];  // [1]
  float* out = (float*)d_out;                    // [2048]
  float* ws  = (float*)d_ws;

#if HAVE_FP8
  if (ws_size >= WS_FP8_BYTES) {
    // precvt10 zeroes the accumulator region itself (blocks 0..7)
    svm_precvt10<<<(NPAD + BQ + 3) / 4, 256, 0, stream>>>(x, s, labels, lambdas, ws);
    svm_main10<<<16 * NG, 256, 0, stream>>>(ws);
    svm_finalize<<<BQ / 256, 256, 0, stream>>>(ws, bias, out);
    return;
  }
#endif
  hipMemsetAsync(ws, 0, BQ * sizeof(float), stream);
  svm_precompute<<<(NPTS + BQ + 3) / 4, 256, 0, stream>>>(x, s, labels, lambdas, ws);
  dim3 grid(391, BQ / 128);
  svm_main<<<grid, 256, 0, stream>>>(x, s, ws);
  svm_finalize<<<BQ / 256, 256, 0, stream>>>(ws, bias, out);
}

// Round 11
// 168.575 us; speedup vs baseline: 3.1656x; 3.1656x over previous
//
#include <hip/hip_runtime.h>
#include <hip/hip_bf16.h>
#include <math.h>

// Problem constants (fixed by the reference)
#define NPTS 50000   // N data points
#define DIM  256     // feature dim (K of the GEMM)
#define BQ   2048    // batch of queries (M of the GEMM)
#define NPAD 50048   // N padded to multiple of 128

#define CH   128     // n-rows per LDS chunk (fp8: 32 KB)
#define NCH  391     // NPAD/CH
#define NG   48      // n-groups; grid = 16 m-tiles x 48 groups = 768
#define LOG2E 1.4426950408889634f

// NOTE: no __has_builtin gating — it differs between host and device passes
// (host pass reports false for amdgcn builtins), which desynchronizes the
// host launch path from the device-compiled kernel set (round-8 crash,
// round-10 silent fallback). The fp8 builtins below are HW-verified on
// gfx950 (guide §3 intrinsic list, m11).

// ---------- fp8 fast-path ws layout (float offsets) ----------
//  acc   [0,      2048)
//  x2h   [2048,   4096)    0.5*log2e*||x||^2
//  t     [4096,  54144)    0.5*log2e*||s||^2 - log2|w|  (+inf when w==0)
//  sgn   [54144, 104192)   label sign
//  xb8   [104192, 235264)  fp8 x rows (256 B each)
//  sb8   [235264, 3438336) fp8 s rows (NPAD, zero-padded)
#define WS_ACC 0
#define WS_X2  2048
#define WS_T   4096
#define WS_SGN 54144
#define WS_XB8 104192
#define WS_SB8 235264
#define WS_FP8_BYTES (3438336ull * 4ull)   // 13,753,344 B

// ---------- v1 fallback layout ----------
#define V1_ACC 0
#define V1_X2  2048
#define V1_S2  4096
#define V1_W   54096

typedef __bf16 bf16x8 __attribute__((ext_vector_type(8)));
typedef __bf16 bf16x4 __attribute__((ext_vector_type(4)));
typedef float  f32x4  __attribute__((ext_vector_type(4)));
typedef long   i64x2  __attribute__((ext_vector_type(2)));
typedef unsigned int u32;

__device__ __forceinline__ float fast_exp2(float v) {
  return __builtin_amdgcn_exp2f(v);   // raw v_exp_f32 (device-verified)
}

__device__ __forceinline__ void async_copy16(const void* g, void* l) {
  __builtin_amdgcn_global_load_lds(
      (const __attribute__((address_space(1))) u32*)g,
      (__attribute__((address_space(3))) u32*)l, 16, 0, 0);
}

// ============================================================
// FP8 FAST PATH (non-scaled v_mfma_f32_16x16x32_fp8_fp8)
// ============================================================

// One wave per row: fp32 -> fp8 e4m3 convert into ws, plus folded epilogue
// constants t = s2h - log2|w| and sign. Blocks 0..7 zero the accumulator.
__global__ __launch_bounds__(256) void svm_precvt10(
    const float* __restrict__ x, const float* __restrict__ s,
    const float* __restrict__ labels, const float* __restrict__ lambdas,
    float* __restrict__ ws) {
  const int wid  = blockIdx.x * 4 + (threadIdx.x >> 6);
  const int lane = threadIdx.x & 63;
  int* xb8 = (int*)(ws + WS_XB8);
  int* sb8 = (int*)(ws + WS_SB8);

  if (blockIdx.x < 8) ws[WS_ACC + blockIdx.x * 256 + threadIdx.x] = 0.0f;

  if (wid < NPAD) {
    float4 v = make_float4(0.f, 0.f, 0.f, 0.f);
    if (wid < NPTS)
      v = reinterpret_cast<const float4*>(s + (size_t)wid * DIM)[lane];
    int pk = __builtin_amdgcn_cvt_pk_fp8_f32(v.x, v.y, 0, false);
    pk     = __builtin_amdgcn_cvt_pk_fp8_f32(v.z, v.w, pk, true);
    sb8[(size_t)wid * 64 + lane] = pk;
    float ss = v.x * v.x + v.y * v.y + v.z * v.z + v.w * v.w;
    #pragma unroll
    for (int off = 32; off > 0; off >>= 1) ss += __shfl_xor(ss, off);
    if (lane == 0) {
      float s2h = 0.5f * LOG2E * ss;
      float lam = (wid < NPTS) ? lambdas[wid] : 0.0f;
      float lab = (wid < NPTS) ? labels[wid] : 1.0f;
      float mag = lam > 0.0f ? lam : 0.0f;
      ws[WS_T + wid]   = (mag > 0.0f) ? s2h - log2f(mag) : __builtin_inff();
      ws[WS_SGN + wid] = lab;
    }
  } else if (wid < NPAD + BQ) {
    int r = wid - NPAD;
    float4 v = reinterpret_cast<const float4*>(x + (size_t)r * DIM)[lane];
    int pk = __builtin_amdgcn_cvt_pk_fp8_f32(v.x, v.y, 0, false);
    pk     = __builtin_amdgcn_cvt_pk_fp8_f32(v.z, v.w, pk, true);
    xb8[(size_t)r * 64 + lane] = pk;
    float ss = v.x * v.x + v.y * v.y + v.z * v.z + v.w * v.w;
    #pragma unroll
    for (int off = 32; off > 0; off >>= 1) ss += __shfl_xor(ss, off);
    if (lane == 0) ws[WS_X2 + r] = 0.5f * LOG2E * ss;
  }
}

// main9 skeleton in fp8: halves LDS read bytes (the ~31-us dominant pipe),
// halves staging, A pinned in 32 VGPR. Row = 256 B fp8 = 16 slots of 16 B;
// LDS stores [n][256B] with slot swizzle: phys slot p holds logical p^(n&15)
// -> both staging writes and fragment reads are conflict-free.
// k-window per (quad, kp, h) = row bytes [quad*64 + kp*16 + h*8, +8),
// applied identically to A and B; the 8 instructions x 4 quads x 8 bytes
// cover all 256 bytes exactly once, so the sum is the true dot product
// (invariant under a shared k-permutation).
__global__ __launch_bounds__(256, 2) void svm_main10(float* __restrict__ ws) {
  __shared__ char sB[CH * 256];  // 32 KB

  const char* xb8 = (const char*)(ws + WS_XB8);
  const char* sb8 = (const char*)(ws + WS_SB8);
  const float* x2g = ws + WS_X2;
  const float* tg  = ws + WS_T;
  const float* sgg = ws + WS_SGN;
  float* accOut    = ws + WS_ACC;

  const int t    = threadIdx.x;
  const int wave = t >> 6;
  const int lane = t & 63;
  const int quad = lane >> 4;
  const int l16  = lane & 15;
  const int g    = blockIdx.x % NG;
  const int mt   = blockIdx.x / NG;       // 0..15
  const int m0w  = mt * 128 + wave * 32;  // this wave's 32 m-rows
  const int c0   = (NCH * g) / NG;
  const int c1   = (NCH * (g + 1)) / NG;

  // A pinned: 2 mi x 4 kp x 16 B = 32 VGPR.
  f32x4 afr[2][4];
  #pragma unroll
  for (int mi = 0; mi < 2; ++mi)
    #pragma unroll
    for (int kp = 0; kp < 4; ++kp)
      afr[mi][kp] = *reinterpret_cast<const f32x4*>(
          xb8 + (size_t)(m0w + mi * 16 + l16) * 256 + quad * 64 + kp * 16);
  #pragma unroll
  for (int mi = 0; mi < 2; ++mi)
    #pragma unroll
    for (int kp = 0; kp < 4; ++kp)
      asm volatile("" : "+v"(afr[mi][kp]));  // no remat, stays in VGPRs

  float runAcc[2][4] = {{0.f, 0.f, 0.f, 0.f}, {0.f, 0.f, 0.f, 0.f}};

  // staging per-lane coords: instr j stages rows j*4..j*4+3 (1 KB).
  const int rowin = lane >> 4;   // 0..3 row within the 4-row group
  const int p     = lane & 15;   // phys slot

  for (int c = c0; c < c1; ++c) {
    __syncthreads();  // prior chunk's LDS reads done

    #pragma unroll
    for (int i = 0; i < 8; ++i) {
      int j = wave * 8 + i;                          // 0..31
      int n15 = ((j & 3) * 4 + rowin) & 15;          // (j*4+rowin) & 15
      const char* src = sb8 + (size_t)(c * CH + j * 4) * 256
                            + rowin * 256 + ((p ^ n15) * 16);
      async_copy16(src, sB + j * 1024 + lane * 16);
    }
    __syncthreads();  // vmcnt drain

    f32x4 acc[2][8];
    #pragma unroll
    for (int mi = 0; mi < 2; ++mi)
      #pragma unroll
      for (int ni = 0; ni < 8; ++ni)
        acc[mi][ni] = (f32x4)(0.0f);

    #pragma unroll
    for (int kp = 0; kp < 4; ++kp) {
      f32x4 bfp[8];
      #pragma unroll
      for (int ni = 0; ni < 8; ++ni) {
        int n = ni * 16 + l16;   // n & 15 == l16
        bfp[ni] = *reinterpret_cast<const f32x4*>(
            sB + n * 256 + (((quad * 4 + kp) ^ l16) * 16));
      }
      #pragma unroll
      for (int h = 0; h < 2; ++h) {
        #pragma unroll
        for (int mi = 0; mi < 2; ++mi) {
          long av = __builtin_bit_cast(i64x2, afr[mi][kp])[h];
          #pragma unroll
          for (int ni = 0; ni < 8; ++ni) {
            long bv = __builtin_bit_cast(i64x2, bfp[ni])[h];
            acc[mi][ni] = __builtin_amdgcn_mfma_f32_16x16x32_fp8_fp8(
                av, bv, acc[mi][ni], 0, 0, 0);
          }
        }
      }
    }

    // Hoisted epilogue: p += sgn * exp2(c*log2e - t_n); x2 applied at end.
    float tt[8], sg[8];
    #pragma unroll
    for (int ni = 0; ni < 8; ++ni) {
      int n = c * CH + ni * 16 + l16;
      tt[ni] = tg[n];
      sg[ni] = sgg[n];
    }
    #pragma unroll
    for (int mi = 0; mi < 2; ++mi)
      #pragma unroll
      for (int reg = 0; reg < 4; ++reg) {
        float pacc = runAcc[mi][reg];
        #pragma unroll
        for (int ni = 0; ni < 8; ++ni)
          pacc = __builtin_fmaf(sg[ni],
                   fast_exp2(__builtin_fmaf(acc[mi][ni][reg], LOG2E, -tt[ni])),
                   pacc);
        runAcc[mi][reg] = pacc;
      }
  }

  // reduce over the 16 n-column lanes; scale by exp2(-x2h); one atomic/row.
  #pragma unroll
  for (int mi = 0; mi < 2; ++mi)
    #pragma unroll
    for (int reg = 0; reg < 4; ++reg) {
      float v = runAcc[mi][reg];
      v += __shfl_xor(v, 1);
      v += __shfl_xor(v, 2);
      v += __shfl_xor(v, 4);
      v += __shfl_xor(v, 8);
      if (l16 == 0) {
        int row = m0w + mi * 16 + quad * 4 + reg;
        atomicAdd(&accOut[row], fast_exp2(-x2g[row]) * v);
      }
    }
}

// ============================================================
// V1 FALLBACK (used only if ws too small)
// ============================================================

__global__ __launch_bounds__(256) void svm_precompute(
    const float* __restrict__ x, const float* __restrict__ s,
    const float* __restrict__ labels, const float* __restrict__ lambdas,
    float* __restrict__ ws) {
  int wid  = blockIdx.x * 4 + (threadIdx.x >> 6);
  int lane = threadIdx.x & 63;
  const float* src;
  if (wid < NPTS)           src = s + (size_t)wid * DIM;
  else if (wid < NPTS + BQ) src = x + (size_t)(wid - NPTS) * DIM;
  else return;
  float4 v = reinterpret_cast<const float4*>(src)[lane];
  float ss = v.x * v.x + v.y * v.y + v.z * v.z + v.w * v.w;
  #pragma unroll
  for (int off = 32; off > 0; off >>= 1) ss += __shfl_xor(ss, off);
  if (lane == 0) {
    if (wid < NPTS) {
      ws[V1_S2 + wid] = ss;
      float lam = lambdas[wid];
      ws[V1_W + wid] = labels[wid] * (lam > 0.0f ? lam : 0.0f);
    } else {
      ws[V1_X2 + (wid - NPTS)] = ss;
    }
  }
}

__global__ __launch_bounds__(256) void svm_main(
    const float* __restrict__ x, const float* __restrict__ s,
    const float* __restrict__ ws) {
  __shared__ __bf16 sA[128 * 32];
  __shared__ __bf16 sB2[128 * 32];

  const int t    = threadIdx.x;
  const int wave = t >> 6;
  const int lane = t & 63;
  const int quad = lane >> 4;
  const int l16  = lane & 15;
  const int wm   = (wave & 1) * 64;
  const int wn   = (wave >> 1) * 64;
  const int bRow0 = blockIdx.y * 128;
  const int n0    = blockIdx.x * 128;

  f32x4 acc[4][4];
  #pragma unroll
  for (int i = 0; i < 4; ++i)
    #pragma unroll
    for (int j = 0; j < 4; ++j)
      acc[i][j] = (f32x4)(0.0f);

  for (int kt = 0; kt < DIM / 32; ++kt) {
    const int k0 = kt * 32;
    __syncthreads();
    #pragma unroll
    for (int i = 0; i < 4; ++i) {
      int slot = t + i * 256;
      int r  = slot >> 3;
      int c4 = slot & 7;
      float4 va = reinterpret_cast<const float4*>(
          x + (size_t)(bRow0 + r) * DIM + k0)[c4];
      bf16x4 ha = { (__bf16)va.x, (__bf16)va.y, (__bf16)va.z, (__bf16)va.w };
      *reinterpret_cast<bf16x4*>(&sA[r * 32 + c4 * 4]) = ha;

      int nrow = n0 + r;
      float4 vb = make_float4(0.f, 0.f, 0.f, 0.f);
      if (nrow < NPTS)
        vb = reinterpret_cast<const float4*>(
            s + (size_t)nrow * DIM + k0)[c4];
      bf16x4 hb = { (__bf16)vb.x, (__bf16)vb.y, (__bf16)vb.z, (__bf16)vb.w };
      *reinterpret_cast<bf16x4*>(&sB2[r * 32 + c4 * 4]) = hb;
    }
    __syncthreads();

    bf16x8 af[4], bfv[4];
    #pragma unroll
    for (int mi = 0; mi < 4; ++mi)
      af[mi] = *reinterpret_cast<const bf16x8*>(
          &sA[(wm + mi * 16 + l16) * 32 + quad * 8]);
    #pragma unroll
    for (int ni = 0; ni < 4; ++ni)
      bfv[ni] = *reinterpret_cast<const bf16x8*>(
          &sB2[(wn + ni * 16 + l16) * 32 + quad * 8]);
    #pragma unroll
    for (int mi = 0; mi < 4; ++mi)
      #pragma unroll
      for (int ni = 0; ni < 4; ++ni)
        acc[mi][ni] = __builtin_amdgcn_mfma_f32_16x16x32_bf16(
            af[mi], bfv[ni], acc[mi][ni], 0, 0, 0);
  }

  const float* x2g = ws + V1_X2;
  const float* s2g = ws + V1_S2;
  const float* wg  = ws + V1_W;
  float* accOut    = (float*)ws + V1_ACC;

  float s2v[4], wv[4];
  #pragma unroll
  for (int ni = 0; ni < 4; ++ni) {
    int n = n0 + wn + ni * 16 + l16;
    bool ok = n < NPTS;
    s2v[ni] = ok ? s2g[n] : 0.0f;
    wv[ni]  = ok ? wg[n]  : 0.0f;
  }
  #pragma unroll
  for (int mi = 0; mi < 4; ++mi) {
    const int mbase = wm + mi * 16 + quad * 4;
    #pragma unroll
    for (int reg = 0; reg < 4; ++reg) {
      float x2r = x2g[bRow0 + mbase + reg];
      float ps = 0.0f;
      #pragma unroll
      for (int ni = 0; ni < 4; ++ni) {
        float cc = acc[mi][ni][reg];
        ps += __expf(__builtin_fmaf(-0.5f, x2r + s2v[ni], cc)) * wv[ni];
      }
      ps += __shfl_xor(ps, 1);
      ps += __shfl_xor(ps, 2);
      ps += __shfl_xor(ps, 4);
      ps += __shfl_xor(ps, 8);
      if (l16 == 0) atomicAdd(&accOut[bRow0 + mbase + reg], ps);
    }
  }
}

// ============================================================

__global__ __launch_bounds__(256) void svm_finalize(
    const float* __restrict__ ws, const float* __restrict__ bias,
    float* __restrict__ out) {
  int i = blockIdx.x * 256 + threadIdx.x;
  if (i < BQ) out[i] = tanhf(ws[i] + bias[0]);  // acc at offset 0 in all layouts
}

extern "C" void kernel_launch(void* const* d_in, const int* in_sizes, int n_in,
                              void* d_out, int out_size, void* d_ws, size_t ws_size,
                              hipStream_t stream) {
  const float* x       = (const float*)d_in[0];  // [2048, 256]
  const float* s       = (const float*)d_in[1];  // [50000, 256]
  const float* labels  = (const float*)d_in[2];  // [50000]
  const float* lambdas = (const float*)d_in[3];  // [50000]
  const float* bias    = (const float*)d_in[4];  // [1]
  float* out = (float*)d_out;                    // [2048]
  float* ws  = (float*)d_ws;

  if (ws_size >= WS_FP8_BYTES) {
    // precvt10 zeroes the accumulator region itself (blocks 0..7)
    svm_precvt10<<<(NPAD + BQ + 3) / 4, 256, 0, stream>>>(x, s, labels, lambdas, ws);
    svm_main10<<<16 * NG, 256, 0, stream>>>(ws);
  } else {
    hipMemsetAsync(ws, 0, BQ * sizeof(float), stream);
    svm_precompute<<<(NPTS + BQ + 3) / 4, 256, 0, stream>>>(x, s, labels, lambdas, ws);
    dim3 grid(391, BQ / 128);
    svm_main<<<grid, 256, 0, stream>>>(x, s, ws);
  }
  svm_finalize<<<BQ / 256, 256, 0, stream>>>(ws, bias, out);
}

// Round 12
// 166.552 us; speedup vs baseline: 3.2041x; 1.0121x over previous
//
#include <hip/hip_runtime.h>
#include <hip/hip_bf16.h>
#include <math.h>

// Problem constants (fixed by the reference)
#define NPTS 50000   // N data points
#define DIM  256     // feature dim (K of the GEMM)
#define BQ   2048    // batch of queries (M of the GEMM)
#define NPAD 50048   // N padded to multiple of 128

#define CH   128     // n-rows per LDS chunk
#define NCH  391     // NPAD/CH
#define NG   48      // n-groups; grid = 16 m-tiles x 48 groups = 768
#define LOG2E 1.4426950408889634f

// NOTE: no __has_builtin gating on amdgcn builtins — host/device passes
// disagree, desynchronizing the host launch path from the device kernel set
// (round-8 crash, round-10 silent fallback).

// ---------- fp8 fast-path ws layout (float offsets) ----------
//  acc   [0,      2048)
//  x2h   [2048,   4096)    0.5*log2e*||x||^2
//  t     [4096,  54144)    0.5*log2e*||s||^2 - log2|w|  (+inf when w==0)
//  sgn   [54144, 104192)   label sign
//  xb8   [104192, 235264)  fp8 x rows (256 B each)
//  sb8   [235264, 3438336) fp8 s rows (NPAD, zero-padded)
#define WS_ACC 0
#define WS_X2  2048
#define WS_T   4096
#define WS_SGN 54144
#define WS_XB8 104192
#define WS_SB8 235264
#define WS_FP8_BYTES (3438336ull * 4ull)   // 13,753,344 B

// ---------- v1 fallback layout ----------
#define V1_ACC 0
#define V1_X2  2048
#define V1_S2  4096
#define V1_W   54096

typedef __bf16 bf16x8 __attribute__((ext_vector_type(8)));
typedef __bf16 bf16x4 __attribute__((ext_vector_type(4)));
typedef float  f32x4  __attribute__((ext_vector_type(4)));
typedef long   i64x2  __attribute__((ext_vector_type(2)));
typedef unsigned int u32;

__device__ __forceinline__ float fast_exp2(float v) {
  return __builtin_amdgcn_exp2f(v);   // raw v_exp_f32
}

__device__ __forceinline__ void async_copy16(const void* g, void* l) {
  __builtin_amdgcn_global_load_lds(
      (const __attribute__((address_space(1))) u32*)g,
      (__attribute__((address_space(3))) u32*)l, 16, 0, 0);
}

// ============================================================
// FP8 FAST PATH (non-scaled v_mfma_f32_16x16x32_fp8_fp8)
// ============================================================

// One wave per row: fp32 -> fp8 e4m3 convert into ws, plus folded epilogue
// constants t = s2h - log2|w| and sign. Blocks 0..7 zero the accumulator.
__global__ __launch_bounds__(256) void svm_precvt10(
    const float* __restrict__ x, const float* __restrict__ s,
    const float* __restrict__ labels, const float* __restrict__ lambdas,
    float* __restrict__ ws) {
  const int wid  = blockIdx.x * 4 + (threadIdx.x >> 6);
  const int lane = threadIdx.x & 63;
  int* xb8 = (int*)(ws + WS_XB8);
  int* sb8 = (int*)(ws + WS_SB8);

  if (blockIdx.x < 8) ws[WS_ACC + blockIdx.x * 256 + threadIdx.x] = 0.0f;

  if (wid < NPAD) {
    float4 v = make_float4(0.f, 0.f, 0.f, 0.f);
    if (wid < NPTS)
      v = reinterpret_cast<const float4*>(s + (size_t)wid * DIM)[lane];
    int pk = __builtin_amdgcn_cvt_pk_fp8_f32(v.x, v.y, 0, false);
    pk     = __builtin_amdgcn_cvt_pk_fp8_f32(v.z, v.w, pk, true);
    sb8[(size_t)wid * 64 + lane] = pk;
    float ss = v.x * v.x + v.y * v.y + v.z * v.z + v.w * v.w;
    #pragma unroll
    for (int off = 32; off > 0; off >>= 1) ss += __shfl_xor(ss, off);
    if (lane == 0) {
      float s2h = 0.5f * LOG2E * ss;
      float lam = (wid < NPTS) ? lambdas[wid] : 0.0f;
      float lab = (wid < NPTS) ? labels[wid] : 1.0f;
      float mag = lam > 0.0f ? lam : 0.0f;
      ws[WS_T + wid]   = (mag > 0.0f) ? s2h - log2f(mag) : __builtin_inff();
      ws[WS_SGN + wid] = lab;
    }
  } else if (wid < NPAD + BQ) {
    int r = wid - NPAD;
    float4 v = reinterpret_cast<const float4*>(x + (size_t)r * DIM)[lane];
    int pk = __builtin_amdgcn_cvt_pk_fp8_f32(v.x, v.y, 0, false);
    pk     = __builtin_amdgcn_cvt_pk_fp8_f32(v.z, v.w, pk, true);
    xb8[(size_t)r * 64 + lane] = pk;
    float ss = v.x * v.x + v.y * v.y + v.z * v.z + v.w * v.w;
    #pragma unroll
    for (int off = 32; off > 0; off >>= 1) ss += __shfl_xor(ss, off);
    if (lane == 0) ws[WS_X2 + r] = 0.5f * LOG2E * ss;
  }
}

// fp8 main in main9's byte-identical LDS geometry (the measured-zero-conflict
// pattern): LDS chunk = [kt=4][n=128][64 B rows], 16-B slots swizzled by the
// 2-bit key ((n&15)>>1)&3. Fragment (kt,quad,h) = row bytes
// [kt*64 + quad*16 + h*8, +8), shared A/B k-mapping (dot invariant; the
// mapping's correctness was verified in round 11, absmax 0.0).
__global__ __launch_bounds__(256, 2) void svm_main12(float* __restrict__ ws) {
  __shared__ char sB[4 * CH * 64];  // 32 KB

  const char* xb8 = (const char*)(ws + WS_XB8);
  const char* sb8 = (const char*)(ws + WS_SB8);
  const float* x2g = ws + WS_X2;
  const float* tg  = ws + WS_T;
  const float* sgg = ws + WS_SGN;
  float* accOut    = ws + WS_ACC;

  const int t    = threadIdx.x;
  const int wave = t >> 6;
  const int lane = t & 63;
  const int quad = lane >> 4;
  const int l16  = lane & 15;
  const int g    = blockIdx.x % NG;
  const int mt   = blockIdx.x / NG;       // 0..15
  const int m0w  = mt * 128 + wave * 32;  // this wave's 32 m-rows
  const int c0   = (NCH * g) / NG;
  const int c1   = (NCH * (g + 1)) / NG;

  // A pinned: 2 mi x 4 kt x 16 B = 32 VGPR.
  // afr[mi][kt] = A row bytes [kt*64 + quad*16, +16)
  f32x4 afr[2][4];
  #pragma unroll
  for (int mi = 0; mi < 2; ++mi)
    #pragma unroll
    for (int kt = 0; kt < 4; ++kt)
      afr[mi][kt] = *reinterpret_cast<const f32x4*>(
          xb8 + (size_t)(m0w + mi * 16 + l16) * 256 + kt * 64 + quad * 16);
  #pragma unroll
  for (int mi = 0; mi < 2; ++mi)
    #pragma unroll
    for (int kt = 0; kt < 4; ++kt)
      asm volatile("" : "+v"(afr[mi][kt]));  // no remat, stays in VGPRs

  float runAcc[2][4] = {{0.f, 0.f, 0.f, 0.f}, {0.f, 0.f, 0.f, 0.f}};

  // staging source swizzle (main9's verified pattern, byte-identical):
  // lane = r*4 + p (r = row in 16-row group, p = phys 16-B slot);
  // phys slot p holds logical slot p ^ ((r>>1)&3).
  const int srcswz = ((lane & 3) ^ ((lane >> 3) & 3)) * 16;  // bytes
  // read-side: logical slot quad lives at phys quad ^ ((l16>>1)&3)
  const int rdswz = (quad ^ ((l16 >> 1) & 3)) * 16;          // bytes

  for (int c = c0; c < c1; ++c) {
    __syncthreads();  // prior chunk's LDS reads done

    // Stage chunk [kt][n][64B]: 32 instrs (8/wave), 1 KB each = 16 rows.
    #pragma unroll
    for (int i = 0; i < 8; ++i) {
      int j  = wave * 8 + i;            // 0..31
      int kt = j >> 3;                  // 0..3
      int nb = (j & 7) * 16;            // 16-row group base
      const char* src = sb8 + (size_t)(c * CH + nb + (lane >> 2)) * 256
                            + kt * 64 + srcswz;
      async_copy16(src, sB + kt * (CH * 64) + nb * 64 + lane * 16);
    }
    __syncthreads();  // vmcnt drain

    f32x4 acc[2][8];
    #pragma unroll
    for (int mi = 0; mi < 2; ++mi)
      #pragma unroll
      for (int ni = 0; ni < 8; ++ni)
        acc[mi][ni] = (f32x4)(0.0f);

    #pragma unroll
    for (int kt = 0; kt < 4; ++kt) {
      f32x4 bfp[8];
      #pragma unroll
      for (int ni = 0; ni < 8; ++ni)
        bfp[ni] = *reinterpret_cast<const f32x4*>(
            sB + kt * (CH * 64) + (ni * 16 + l16) * 64 + rdswz);
      #pragma unroll
      for (int h = 0; h < 2; ++h) {
        #pragma unroll
        for (int mi = 0; mi < 2; ++mi) {
          long av = __builtin_bit_cast(i64x2, afr[mi][kt])[h];
          #pragma unroll
          for (int ni = 0; ni < 8; ++ni) {
            long bv = __builtin_bit_cast(i64x2, bfp[ni])[h];
            acc[mi][ni] = __builtin_amdgcn_mfma_f32_16x16x32_fp8_fp8(
                av, bv, acc[mi][ni], 0, 0, 0);
          }
        }
      }
    }

    // Hoisted epilogue: p += sgn * exp2(c*log2e - t_n); x2 applied at end.
    float tt[8], sg[8];
    #pragma unroll
    for (int ni = 0; ni < 8; ++ni) {
      int n = c * CH + ni * 16 + l16;
      tt[ni] = tg[n];
      sg[ni] = sgg[n];
    }
    #pragma unroll
    for (int mi = 0; mi < 2; ++mi)
      #pragma unroll
      for (int reg = 0; reg < 4; ++reg) {
        float pacc = runAcc[mi][reg];
        #pragma unroll
        for (int ni = 0; ni < 8; ++ni)
          pacc = __builtin_fmaf(sg[ni],
                   fast_exp2(__builtin_fmaf(acc[mi][ni][reg], LOG2E, -tt[ni])),
                   pacc);
        runAcc[mi][reg] = pacc;
      }
  }

  // reduce over the 16 n-column lanes; scale by exp2(-x2h); one atomic/row.
  #pragma unroll
  for (int mi = 0; mi < 2; ++mi)
    #pragma unroll
    for (int reg = 0; reg < 4; ++reg) {
      float v = runAcc[mi][reg];
      v += __shfl_xor(v, 1);
      v += __shfl_xor(v, 2);
      v += __shfl_xor(v, 4);
      v += __shfl_xor(v, 8);
      if (l16 == 0) {
        int row = m0w + mi * 16 + quad * 4 + reg;
        atomicAdd(&accOut[row], fast_exp2(-x2g[row]) * v);
      }
    }
}

// ============================================================
// V1 FALLBACK (used only if ws too small)
// ============================================================

__global__ __launch_bounds__(256) void svm_precompute(
    const float* __restrict__ x, const float* __restrict__ s,
    const float* __restrict__ labels, const float* __restrict__ lambdas,
    float* __restrict__ ws) {
  int wid  = blockIdx.x * 4 + (threadIdx.x >> 6);
  int lane = threadIdx.x & 63;
  const float* src;
  if (wid < NPTS)           src = s + (size_t)wid * DIM;
  else if (wid < NPTS + BQ) src = x + (size_t)(wid - NPTS) * DIM;
  else return;
  float4 v = reinterpret_cast<const float4*>(src)[lane];
  float ss = v.x * v.x + v.y * v.y + v.z * v.z + v.w * v.w;
  #pragma unroll
  for (int off = 32; off > 0; off >>= 1) ss += __shfl_xor(ss, off);
  if (lane == 0) {
    if (wid < NPTS) {
      ws[V1_S2 + wid] = ss;
      float lam = lambdas[wid];
      ws[V1_W + wid] = labels[wid] * (lam > 0.0f ? lam : 0.0f);
    } else {
      ws[V1_X2 + (wid - NPTS)] = ss;
    }
  }
}

__global__ __launch_bounds__(256) void svm_main(
    const float* __restrict__ x, const float* __restrict__ s,
    const float* __restrict__ ws) {
  __shared__ __bf16 sA[128 * 32];
  __shared__ __bf16 sB2[128 * 32];

  const int t    = threadIdx.x;
  const int wave = t >> 6;
  const int lane = t & 63;
  const int quad = lane >> 4;
  const int l16  = lane & 15;
  const int wm   = (wave & 1) * 64;
  const int wn   = (wave >> 1) * 64;
  const int bRow0 = blockIdx.y * 128;
  const int n0    = blockIdx.x * 128;

  f32x4 acc[4][4];
  #pragma unroll
  for (int i = 0; i < 4; ++i)
    #pragma unroll
    for (int j = 0; j < 4; ++j)
      acc[i][j] = (f32x4)(0.0f);

  for (int kt = 0; kt < DIM / 32; ++kt) {
    const int k0 = kt * 32;
    __syncthreads();
    #pragma unroll
    for (int i = 0; i < 4; ++i) {
      int slot = t + i * 256;
      int r  = slot >> 3;
      int c4 = slot & 7;
      float4 va = reinterpret_cast<const float4*>(
          x + (size_t)(bRow0 + r) * DIM + k0)[c4];
      bf16x4 ha = { (__bf16)va.x, (__bf16)va.y, (__bf16)va.z, (__bf16)va.w };
      *reinterpret_cast<bf16x4*>(&sA[r * 32 + c4 * 4]) = ha;

      int nrow = n0 + r;
      float4 vb = make_float4(0.f, 0.f, 0.f, 0.f);
      if (nrow < NPTS)
        vb = reinterpret_cast<const float4*>(
            s + (size_t)nrow * DIM + k0)[c4];
      bf16x4 hb = { (__bf16)vb.x, (__bf16)vb.y, (__bf16)vb.z, (__bf16)vb.w };
      *reinterpret_cast<bf16x4*>(&sB2[r * 32 + c4 * 4]) = hb;
    }
    __syncthreads();

    bf16x8 af[4], bfv[4];
    #pragma unroll
    for (int mi = 0; mi < 4; ++mi)
      af[mi] = *reinterpret_cast<const bf16x8*>(
          &sA[(wm + mi * 16 + l16) * 32 + quad * 8]);
    #pragma unroll
    for (int ni = 0; ni < 4; ++ni)
      bfv[ni] = *reinterpret_cast<const bf16x8*>(
          &sB2[(wn + ni * 16 + l16) * 32 + quad * 8]);
    #pragma unroll
    for (int mi = 0; mi < 4; ++mi)
      #pragma unroll
      for (int ni = 0; ni < 4; ++ni)
        acc[mi][ni] = __builtin_amdgcn_mfma_f32_16x16x32_bf16(
            af[mi], bfv[ni], acc[mi][ni], 0, 0, 0);
  }

  const float* x2g = ws + V1_X2;
  const float* s2g = ws + V1_S2;
  const float* wg  = ws + V1_W;
  float* accOut    = (float*)ws + V1_ACC;

  float s2v[4], wv[4];
  #pragma unroll
  for (int ni = 0; ni < 4; ++ni) {
    int n = n0 + wn + ni * 16 + l16;
    bool ok = n < NPTS;
    s2v[ni] = ok ? s2g[n] : 0.0f;
    wv[ni]  = ok ? wg[n]  : 0.0f;
  }
  #pragma unroll
  for (int mi = 0; mi < 4; ++mi) {
    const int mbase = wm + mi * 16 + quad * 4;
    #pragma unroll
    for (int reg = 0; reg < 4; ++reg) {
      float x2r = x2g[bRow0 + mbase + reg];
      float ps = 0.0f;
      #pragma unroll
      for (int ni = 0; ni < 4; ++ni) {
        float cc = acc[mi][ni][reg];
        ps += __expf(__builtin_fmaf(-0.5f, x2r + s2v[ni], cc)) * wv[ni];
      }
      ps += __shfl_xor(ps, 1);
      ps += __shfl_xor(ps, 2);
      ps += __shfl_xor(ps, 4);
      ps += __shfl_xor(ps, 8);
      if (l16 == 0) atomicAdd(&accOut[bRow0 + mbase + reg], ps);
    }
  }
}

// ============================================================

__global__ __launch_bounds__(256) void svm_finalize(
    const float* __restrict__ ws, const float* __restrict__ bias,
    float* __restrict__ out) {
  int i = blockIdx.x * 256 + threadIdx.x;
  if (i < BQ) out[i] = tanhf(ws[i] + bias[0]);  // acc at offset 0 in all layouts
}

extern "C" void kernel_launch(void* const* d_in, const int* in_sizes, int n_in,
                              void* d_out, int out_size, void* d_ws, size_t ws_size,
                              hipStream_t stream) {
  const float* x       = (const float*)d_in[0];  // [2048, 256]
  const float* s       = (const float*)d_in[1];  // [50000, 256]
  const float* labels  = (const float*)d_in[2];  // [50000]
  const float* lambdas = (const float*)d_in[3];  // [50000]
  const float* bias    = (const float*)d_in[4];  // [1]
  float* out = (float*)d_out;                    // [2048]
  float* ws  = (float*)d_ws;

  if (ws_size >= WS_FP8_BYTES) {
    // precvt10 zeroes the accumulator region itself (blocks 0..7)
    svm_precvt10<<<(NPAD + BQ + 3) / 4, 256, 0, stream>>>(x, s, labels, lambdas, ws);
    svm_main12<<<16 * NG, 256, 0, stream>>>(ws);
  } else {
    hipMemsetAsync(ws, 0, BQ * sizeof(float), stream);
    svm_precompute<<<(NPTS + BQ + 3) / 4, 256, 0, stream>>>(x, s, labels, lambdas, ws);
    dim3 grid(391, BQ / 128);
    svm_main<<<grid, 256, 0, stream>>>(x, s, ws);
  }
  svm_finalize<<<BQ / 256, 256, 0, stream>>>(ws, bias, out);
}